// Round 2
// baseline (185.521 us; speedup 1.0000x reference)
//
#include <hip/hip_runtime.h>
#include <hip/hip_bf16.h>
#include <math.h>

// Problem constants
#define B_ 8
#define C_ 64
#define H_ 256
#define W_ 256
#define HL_ 128
#define WL_ 128
#define GN_G 8
#define CPG 8
#define GRP 4
#define OC_ 8
#define GROUP_ELEMS (CPG * H_ * W_)   // 524288

#define TILE_H 16       // low-res rows per k2 block
#define XROWS 34        // hi-res rows staged (2*16 + 2 halo)
#define LDSW 264        // LDS row stride in floats (16B-aligned stores at col 4)

// ---------------- Kernel 2': fused GN-partials + pool(x) + pool(L(x)) ----------------
// grid: (b,c) * 8 row-tiles = 4096 blocks, 256 threads
__global__ __launch_bounds__(256) void k2_fused(const float* __restrict__ x,
                                                const float* __restrict__ hpw,
                                                float* __restrict__ px,
                                                float* __restrict__ pL,
                                                float* __restrict__ partials) {
  __shared__ float tile[XROWS * LDSW];   // ~35.9 KB
  __shared__ float rs[4], rs2[4];
  const int t = threadIdx.x;
  const int blk = blockIdx.x;
  const int tileIdx = blk & 7;
  const int bc = blk >> 3;               // b*64+c
  const int c = bc & 63;
  const int hl0 = tileIdx * TILE_H;
  const float* plane = x + (size_t)bc * (H_ * W_);
  const int y0 = 2 * hl0 - 1;

  // zero the two sentinel columns (col 3 <-> x=-1, col 260 <-> x=256)
  if (t < XROWS * 2) {
    const int r = t >> 1;
    tile[r * LDSW + ((t & 1) ? 260 : 3)] = 0.f;
  }

  // stage x rows [y0, y0+33] as float4, accumulate GN partial sums on owned rows
  float s = 0.f, s2 = 0.f;
  for (int i = 0; i < 9; ++i) {
    const int q = t + i * 256;
    if (q >= XROWS * 64) break;
    const int r = q >> 6;
    const int c4 = (q & 63) << 2;
    const int y = y0 + r;
    float4 v = make_float4(0.f, 0.f, 0.f, 0.f);
    if ((unsigned)y < (unsigned)H_)
      v = *reinterpret_cast<const float4*>(plane + y * W_ + c4);
    *reinterpret_cast<float4*>(&tile[r * LDSW + 4 + c4]) = v;
    if (r >= 1 && r <= 32) {   // owned rows: exactly hi-res rows 2*hl0 .. 2*hl0+31
      s  += v.x + v.y + v.z + v.w;
      s2 += v.x * v.x + v.y * v.y + v.z * v.z + v.w * v.w;
    }
  }
#pragma unroll
  for (int off = 32; off > 0; off >>= 1) {
    s  += __shfl_down(s, off, 64);
    s2 += __shfl_down(s2, off, 64);
  }
  if ((t & 63) == 0) { rs[t >> 6] = s; rs2[t >> 6] = s2; }
  __syncthreads();
  if (t == 0) {
    partials[blk * 2 + 0] = rs[0] + rs[1] + rs[2] + rs[3];
    partials[blk * 2 + 1] = rs2[0] + rs2[1] + rs2[2] + rs2[3];
  }

  // depthwise weights (wave-uniform: c uniform per block)
  float w[9];
#pragma unroll
  for (int i = 0; i < 9; ++i) w[i] = hpw[c * 9 + i];

  // compute 8 vertical outputs per thread from LDS with rolling 4x4 window
  const int wl = t & 127;
  const int hs = (t >> 7) * 8;           // 0 or 8
  const int colb = 3 + 2 * wl;
  const int rbase = 2 * hs;
  float win[4][4];
#pragma unroll
  for (int j = 0; j < 4; ++j)
#pragma unroll
    for (int d = 0; d < 4; ++d)
      win[j][d] = tile[(rbase + j) * LDSW + colb + d];

  int outIdx = (bc * HL_ + (hl0 + hs)) * WL_ + wl;
#pragma unroll
  for (int i = 0; i < 8; ++i) {
    // 2x2 presums: p[j][d] = win[j][d]+win[j][d+1]; q[j][d] = p[j][d]+p[j+1][d]
    float pr[4][3];
#pragma unroll
    for (int j = 0; j < 4; ++j)
#pragma unroll
      for (int d = 0; d < 3; ++d) pr[j][d] = win[j][d] + win[j][d + 1];
    float hfsum = 0.f;
    float q11 = 0.f;
#pragma unroll
    for (int j = 0; j < 3; ++j)
#pragma unroll
      for (int d = 0; d < 3; ++d) {
        const float qq = pr[j][d] + pr[j + 1][d];
        hfsum = fmaf(w[j * 3 + d], qq, hfsum);
        if (j == 1 && d == 1) q11 = qq;
      }
    px[outIdx] = 0.25f * q11;
    pL[outIdx] = 0.25f * hfsum;
    outIdx += WL_;
    if (i < 7) {
      const int rn = rbase + 2 * i + 4;
#pragma unroll
      for (int d = 0; d < 4; ++d) {
        win[0][d] = win[2][d];
        win[1][d] = win[3][d];
        win[2][d] = tile[rn * LDSW + colb + d];
        win[3][d] = tile[(rn + 1) * LDSW + colb + d];
      }
    }
  }
}

// ---------------- Kernel 1b: finalize per-(b,c) affine ----------------
// 1 block, 512 threads: t = b*64+c ; partials indexed by k2 block id = (bc*8+tile)
__global__ __launch_bounds__(512) void k1_finish(const float* __restrict__ partials,
                                                 const float* __restrict__ gamma,
                                                 const float* __restrict__ beta,
                                                 float* __restrict__ ab) {
  const int t = threadIdx.x;
  const int b = t >> 6, c = t & 63, g = c >> 3;
  float S = 0.f, S2 = 0.f;
  for (int c2 = g * CPG; c2 < g * CPG + CPG; ++c2)
#pragma unroll
    for (int p = 0; p < 8; ++p) {
      const int blk = (b * 64 + c2) * 8 + p;
      S  += partials[blk * 2 + 0];
      S2 += partials[blk * 2 + 1];
    }
  const float N = (float)GROUP_ELEMS;
  const float mean = S / N;
  const float var = fmaxf(S2 / N - mean * mean, 0.f);
  const float a = rsqrtf(var + 1e-5f) * gamma[c];
  ab[t * 2 + 0] = a;
  ab[t * 2 + 1] = beta[c] - mean * a;
}

// ---------------- Kernel 3': affine + direction feat + gates -> sample grid ----------------
// thread per low-res pixel (b,hl,wl)
__global__ __launch_bounds__(256) void k3_offset(const float* __restrict__ px,
                                                 const float* __restrict__ pL,
                                                 const float* __restrict__ ab,
                                                 const float* __restrict__ dir_w,
                                                 const float* __restrict__ dir_b,
                                                 const float* __restrict__ mag_w,
                                                 const float* __restrict__ mag_b,
                                                 const float* __restrict__ hfg_w,
                                                 const float* __restrict__ hfg_b,
                                                 float2* __restrict__ grid) {
  __shared__ float s_mag[OC_ * C_], s_hfg[OC_ * C_], s_dir[OC_ * 8], s_b[3 * OC_], s_ab[128];
  const int tid = threadIdx.x;
  const int idx = blockIdx.x * 256 + tid;   // B*HL*WL = 131072
  const int wl = idx & (WL_ - 1);
  const int hl = (idx >> 7) & (HL_ - 1);
  const int b = idx >> 14;                  // uniform per block (256 | 16384)

  for (int i = tid; i < OC_ * C_; i += 256) { s_mag[i] = mag_w[i]; s_hfg[i] = hfg_w[i]; }
  if (tid < OC_ * 8) s_dir[tid] = dir_w[tid];
  if (tid < OC_) { s_b[tid] = mag_b[tid]; s_b[OC_ + tid] = hfg_b[tid]; s_b[2 * OC_ + tid] = dir_b[tid]; }
  if (tid < 128) s_ab[tid] = ab[b * 128 + tid];
  __syncthreads();

  float dot[9], n2[9];
#pragma unroll
  for (int k = 0; k < 9; ++k) { dot[k] = 0.f; n2[k] = 0.f; }
  float n1 = 0.f;
  float mago[OC_], hfgo[OC_];
#pragma unroll
  for (int o = 0; o < OC_; ++o) { mago[o] = 0.f; hfgo[o] = 0.f; }

  const float mterm = 0.5f * ((hl == 0) + (hl == HL_ - 1) + (wl == 0) + (wl == WL_ - 1));
  const int pbase = ((b * C_) * HL_ + hl) * WL_ + wl;
  for (int c = 0; c < C_; ++c) {
    const float a = s_ab[2 * c], bb = s_ab[2 * c + 1];
    const float* p = px + pbase + c * (HL_ * WL_);
    const float vc = fmaf(a, p[0], bb);
    n1 = fmaf(vc, vc, n1);
#pragma unroll
    for (int k = 0; k < 9; ++k) {
      if (k == 4) continue;
      const int di = k / 3 - 1, dj = k % 3 - 1;
      const int y = hl + di, xx = wl + dj;
      const bool ok = ((unsigned)y < (unsigned)HL_) && ((unsigned)xx < (unsigned)WL_);
      const float v = ok ? fmaf(a, p[di * WL_ + dj], bb) : 0.f;
      dot[k] = fmaf(vc, v, dot[k]);
      n2[k] = fmaf(v, v, n2[k]);
    }
    const float vh = fmaf(a, pL[pbase + c * (HL_ * WL_)], bb * mterm);
#pragma unroll
    for (int o = 0; o < OC_; ++o) {
      mago[o] = fmaf(s_mag[o * C_ + c], vc, mago[o]);
      hfgo[o] = fmaf(s_hfg[o * C_ + c], vh, hfgo[o]);
    }
  }

  const float n1c = fmaxf(sqrtf(n1), 1e-8f);
  float df[8];
#pragma unroll
  for (int k = 0; k < 9; ++k) {
    if (k == 4) continue;
    const int j = (k < 4) ? k : k - 1;
    df[j] = dot[k] / (n1c * fmaxf(sqrtf(n2[k]), 1e-8f));
  }

  float off[OC_];
#pragma unroll
  for (int o = 0; o < OC_; ++o) {
    float t1 = s_b[2 * OC_ + o];
#pragma unroll
    for (int j = 0; j < 8; ++j) t1 = fmaf(s_dir[o * 8 + j], df[j], t1);
    const float z = mago[o] + s_b[o] + hfgo[o] + s_b[OC_ + o];
    const float gate = 1.f / (1.f + expf(-z));
    off[o] = t1 * gate;
  }

#pragma unroll
  for (int g = 0; g < GRP; ++g) {
    const float ix = fminf(fmaxf(2.f * wl + 0.5f + off[g], 0.f), (float)(W_ - 1));
    const float iy = fminf(fmaxf(2.f * hl + 0.5f + off[GRP + g], 0.f), (float)(H_ - 1));
    grid[((b * GRP + g) * (HL_ * WL_)) + hl * WL_ + wl] = make_float2(ix, iy);
  }
}

// ---------------- Kernel 4: bilinear grid sample (border) ----------------
__global__ __launch_bounds__(256) void k4_sample(const float* __restrict__ x,
                                                 const float2* __restrict__ grid,
                                                 float* __restrict__ out) {
  const int idx = blockIdx.x * 256 + threadIdx.x;
  const int wl = idx & (WL_ - 1);
  const int hl = (idx >> 7) & (HL_ - 1);
  const int bc = idx >> 14;
  const int c = bc & 63;
  const int b = bc >> 6;
  const int g = c >> 4;
  const float2 G = grid[(b * GRP + g) * (HL_ * WL_) + hl * WL_ + wl];
  const float ix = G.x, iy = G.y;
  const float x0f = floorf(ix), y0f = floorf(iy);
  const float wx = ix - x0f, wy = iy - y0f;
  const int x0 = (int)x0f, y0 = (int)y0f;
  const int x1 = min(x0 + 1, W_ - 1), y1 = min(y0 + 1, H_ - 1);
  const float* plane = x + (size_t)bc * (H_ * W_);
  const float v00 = plane[y0 * W_ + x0];
  const float v01 = plane[y0 * W_ + x1];
  const float v10 = plane[y1 * W_ + x0];
  const float v11 = plane[y1 * W_ + x1];
  out[idx] = v00 * (1.f - wx) * (1.f - wy) + v01 * wx * (1.f - wy)
           + v10 * (1.f - wx) * wy + v11 * wx * wy;
}

extern "C" void kernel_launch(void* const* d_in, const int* in_sizes, int n_in,
                              void* d_out, int out_size, void* d_ws, size_t ws_size,
                              hipStream_t stream) {
  const float* x = (const float*)d_in[0];
  const float* gn_gamma = (const float*)d_in[1];
  const float* gn_beta = (const float*)d_in[2];
  const float* hp_weight = (const float*)d_in[3];
  const float* dir_w = (const float*)d_in[4];
  const float* dir_b = (const float*)d_in[5];
  const float* mag_w = (const float*)d_in[6];
  const float* mag_b = (const float*)d_in[7];
  const float* hfg_w = (const float*)d_in[8];
  const float* hfg_b = (const float*)d_in[9];
  float* out = (float*)d_out;

  // ws layout (floats)
  float* ws = (float*)d_ws;
  float* partials = ws;                                  // 8192
  float* ab = ws + 8192;                                 // 1024
  float* px = ws + 16384;                                // 2,097,152
  float* pL = px + (size_t)B_ * C_ * HL_ * WL_;          // 2,097,152
  float2* grid = (float2*)(pL + (size_t)B_ * C_ * HL_ * WL_);  // 1,048,576 floats

  k2_fused<<<B_ * C_ * 8, 256, 0, stream>>>(x, hp_weight, px, pL, partials);
  k1_finish<<<1, 512, 0, stream>>>(partials, gn_gamma, gn_beta, ab);
  k3_offset<<<(B_ * HL_ * WL_) / 256, 256, 0, stream>>>(px, pL, ab, dir_w, dir_b,
                                                        mag_w, mag_b, hfg_w, hfg_b, grid);
  k4_sample<<<(B_ * C_ * HL_ * WL_) / 256, 256, 0, stream>>>(x, grid, out);
}